// Round 1
// baseline (702.281 us; speedup 1.0000x reference)
//
#include <hip/hip_runtime.h>
#include <hip/hip_bf16.h>

typedef _Float16 half8 __attribute__((ext_vector_type(8)));
typedef float floatx4 __attribute__((ext_vector_type(4)));

#define SEQ 2048
#define DIM 2048
#define HQ 32
#define HKV 8
#define HD 64
#define NQ (HQ*HD)    /* 2048 */
#define NK (HKV*HD)   /* 512  */
#define NTOT (NQ+NK)  /* 2560 */
#define LOG2E 1.44269504088896340736f

#define GLOAD_LDS16(g, l) \
    __builtin_amdgcn_global_load_lds( \
        (const __attribute__((address_space(1))) void*)(g), \
        (__attribute__((address_space(3))) void*)(l), 16, 0, 0)

// ---------------------------------------------------------------------------
// Kernel 0: fp32 -> fp16 conversion, vectorized: float4 x2 -> half8 per thread
// ---------------------------------------------------------------------------
__global__ __launch_bounds__(256) void convert_kernel(
    const float* __restrict__ X, const float* __restrict__ Wq,
    const float* __restrict__ Wk, _Float16* __restrict__ Xh,
    _Float16* __restrict__ Wh)
{
    const long c   = (long)blockIdx.x * 256 + threadIdx.x;  // 8-float chunk id
    const long nxc = (long)SEQ * DIM / 8;                   // 524288
    const float* src;
    _Float16* dst;
    if (c < nxc) {
        src = X + c * 8;
        dst = Xh + c * 8;
    } else {
        long f = (c - nxc) * 8;
        src = (f < (long)NQ * DIM) ? Wq + f : Wk + (f - (long)NQ * DIM);
        dst = Wh + f;
    }
    float4 a = ((const float4*)src)[0];
    float4 b = ((const float4*)src)[1];
    half8 h = {(_Float16)a.x, (_Float16)a.y, (_Float16)a.z, (_Float16)a.w,
               (_Float16)b.x, (_Float16)b.y, (_Float16)b.z, (_Float16)b.w};
    *(half8*)dst = h;
}

// ---------------------------------------------------------------------------
// Kernel 1: QK projection GEMM + RoPE. m97-class structure: BM=128, BN=128,
// BK=64. 256 threads = 4 waves (2x2), wave tile 64x64, acc[4][4].
// global_load_lds staging with XOR chunk swizzle applied on the GLOBAL
// address (LDS DMA destination stays linear, per gfx950 constraint).
// Q output is pre-scaled by log2(e) so the attention kernel can use exp2.
// ---------------------------------------------------------------------------
__global__ __launch_bounds__(256) void gemm1_kernel(
    const _Float16* __restrict__ Xh, const _Float16* __restrict__ Wh,
    const float* __restrict__ cosb, const float* __restrict__ sinb,
    _Float16* __restrict__ qout, _Float16* __restrict__ kout)
{
    __shared__ __align__(16) _Float16 lsA[128 * 64];   // 16 KB
    __shared__ __align__(16) _Float16 lsB[128 * 64];   // 16 KB
    const int tid  = threadIdx.x;
    const int lane = tid & 63;
    const int wv   = tid >> 6;
    const int wm   = wv & 1, wn = wv >> 1;       // 2x2 wave grid, 64x64 each
    const int m    = lane & 15, quad = lane >> 4;
    const int s0   = blockIdx.x * 128;
    const int n0   = blockIdx.y * 128;

    floatx4 acc[4][4];
    #pragma unroll
    for (int i = 0; i < 4; i++)
        #pragma unroll
        for (int j = 0; j < 4; j++)
            acc[i][j] = floatx4{0.f, 0.f, 0.f, 0.f};

    for (int k0 = 0; k0 < DIM; k0 += 64) {
        __syncthreads();
        // A: 128 rows x 8 chunks(16B) = 1024 chunks, 4 rounds of 256 threads
        #pragma unroll
        for (int r = 0; r < 4; r++) {
            int c    = r * 256 + tid;
            int row  = c >> 3;
            int chg  = (c & 7) ^ (row & 7);   // swizzled global chunk
            GLOAD_LDS16(Xh + (long)(s0 + row) * DIM + k0 + chg * 8,
                        (char*)lsA + (r * 256 + wv * 64) * 16);
        }
        // B: 128 rows x 8 chunks = 1024 chunks, 4 rounds
        #pragma unroll
        for (int r = 0; r < 4; r++) {
            int c    = r * 256 + tid;
            int row  = c >> 3;
            int chg  = (c & 7) ^ (row & 7);
            GLOAD_LDS16(Wh + (long)(n0 + row) * DIM + k0 + chg * 8,
                        (char*)lsB + (r * 256 + wv * 64) * 16);
        }
        __syncthreads();   // drains vmcnt + lgkmcnt

        #pragma unroll
        for (int kk = 0; kk < 2; kk++) {
            half8 aF[4], bF[4];
            const int pc = ((kk << 2) | quad) ^ (m & 7);
            #pragma unroll
            for (int i = 0; i < 4; i++)
                aF[i] = *(const half8*)(lsA + (wm * 64 + i * 16 + m) * 64 + pc * 8);
            #pragma unroll
            for (int j = 0; j < 4; j++)
                bF[j] = *(const half8*)(lsB + (wn * 64 + j * 16 + m) * 64 + pc * 8);
            #pragma unroll
            for (int i = 0; i < 4; i++)
                #pragma unroll
                for (int j = 0; j < 4; j++)
                    acc[i][j] = __builtin_amdgcn_mfma_f32_16x16x32_f16(
                        aF[i], bF[j], acc[i][j], 0, 0, 0);
        }
    }

    // Epilogue: RoPE + fp16 store. Wave covers 64 cols = one head exactly
    // (n0 multiple of 128, +wn*64). Q additionally scaled by log2(e).
    #pragma unroll
    for (int i = 0; i < 4; i++) {
        #pragma unroll
        for (int reg = 0; reg < 4; reg++) {
            int s = s0 + wm * 64 + i * 16 + quad * 4 + reg;
            #pragma unroll
            for (int j = 0; j < 4; j++) {
                int col = n0 + wn * 64 + j * 16 + m;
                int d   = j * 16 + m;
                float v = acc[i][j][reg];
                float partner = (j < 2) ? -acc[i][j + 2][reg] : acc[i][j - 2][reg];
                float cs = cosb[s * HD + d];
                float sn = sinb[s * HD + d];
                float o  = v * cs + partner * sn;
                if (col < NQ) {
                    int hq = col >> 6;
                    qout[((long)hq * SEQ + s) * HD + d] = (_Float16)(o * LOG2E);
                } else {
                    int hk = (col - NQ) >> 6;
                    kout[((long)hk * SEQ + s) * HD + d] = (_Float16)o;
                }
            }
        }
    }
}

// ---------------------------------------------------------------------------
// Kernel 2: scores + softmax. Block = (16 q-rows, head), 512 threads (8 waves).
// Operand-swapped MFMA: A = K-tile (M = key), B = Q-tile (N = query).
// C layout: col(lane&15) = query, row(quad*4+reg) = key -> each lane holds
// 4 CONSECUTIVE keys of ONE query row => float4 stores, scalar softmax state.
// Q arrives pre-scaled by log2(e) so exp is a single v_exp_f32 (exp2).
// K loads run a 2-deep software pipeline ahead of the MFMAs.
// ---------------------------------------------------------------------------
__global__ __launch_bounds__(512) void attn_kernel(
    const _Float16* __restrict__ qf, const _Float16* __restrict__ kf,
    float* __restrict__ out)
{
    __shared__ float redm[8][16];
    __shared__ float redl[8][16];
    const int tid  = threadIdx.x;
    const int lane = tid & 63;
    const int w    = tid >> 6;      // wave 0..7, owns keys [w*256, w*256+256)
    const int m    = lane & 15, quad = lane >> 4;
    const int qb   = blockIdx.x;    // 0..127
    const int h    = blockIdx.y;    // 0..31
    const int kvh  = h >> 2;
    const int s0   = qb * 16;

    const _Float16* qbase = qf + ((long)h * SEQ + s0) * HD;
    const _Float16* kbase = kf + (long)kvh * SEQ * HD;

    // B operand = Q: B[n=lane&15][k=quad*8+j]
    half8 bQ0 = *(const half8*)(qbase + (long)m * HD + quad * 8);
    half8 bQ1 = *(const half8*)(qbase + (long)m * HD + 32 + quad * 8);

    floatx4 acc[16];
    // prologue: load ct=0 tile
    const _Float16* kp = kbase + (long)(w * 256 + m) * HD + quad * 8;
    half8 aK0 = *(const half8*)(kp);
    half8 aK1 = *(const half8*)(kp + 32);
    #pragma unroll
    for (int ct = 0; ct < 16; ct++) {
        half8 nK0, nK1;
        if (ct < 15) {   // compile-time folded after unroll
            const _Float16* np = kbase + (long)(w * 256 + (ct + 1) * 16 + m) * HD + quad * 8;
            nK0 = *(const half8*)(np);
            nK1 = *(const half8*)(np + 32);
        }
        floatx4 a = floatx4{0.f, 0.f, 0.f, 0.f};
        a = __builtin_amdgcn_mfma_f32_16x16x32_f16(aK0, bQ0, a, 0, 0, 0);
        a = __builtin_amdgcn_mfma_f32_16x16x32_f16(aK1, bQ1, a, 0, 0, 0);
        acc[ct] = a;
        aK0 = nK0;
        aK1 = nK1;
    }

    // Each lane: one q-row (q = s0+m), 64 key-values (16 ct x 4 reg).
    float lm = acc[0][0];
    #pragma unroll
    for (int ct = 0; ct < 16; ct++)
        #pragma unroll
        for (int r = 0; r < 4; r++) lm = fmaxf(lm, acc[ct][r]);
    lm = fmaxf(lm, __shfl_xor(lm, 16));
    lm = fmaxf(lm, __shfl_xor(lm, 32));
    if (quad == 0) redm[w][m] = lm;
    __syncthreads();
    float g = redm[0][m];
    #pragma unroll
    for (int ww = 1; ww < 8; ww++) g = fmaxf(g, redm[ww][m]);

    float ls = 0.f;
    #pragma unroll
    for (int ct = 0; ct < 16; ct++) {
        #pragma unroll
        for (int r = 0; r < 4; r++) {
            float e = exp2f(acc[ct][r] - g);   // scores pre-scaled by log2(e)
            acc[ct][r] = e;
            ls += e;
        }
    }
    ls += __shfl_xor(ls, 16);
    ls += __shfl_xor(ls, 32);
    if (quad == 0) redl[w][m] = ls;
    __syncthreads();
    float tot = 0.f;
    #pragma unroll
    for (int ww = 0; ww < 8; ww++) tot += redl[ww][m];
    float inv = 1.0f / tot;

    // float4 stores: lane writes keys [n0+quad*4, +4) of row q=s0+m
    float* obase = out + ((long)h * SEQ + s0 + m) * SEQ + w * 256 + quad * 4;
    #pragma unroll
    for (int ct = 0; ct < 16; ct++) {
        floatx4 v = acc[ct];
        v[0] *= inv; v[1] *= inv; v[2] *= inv; v[3] *= inv;
        *(floatx4*)(obase + ct * 16) = v;
    }
}

// ---------------------------------------------------------------------------
extern "C" void kernel_launch(void* const* d_in, const int* in_sizes, int n_in,
                              void* d_out, int out_size, void* d_ws, size_t ws_size,
                              hipStream_t stream) {
    const float* hidden = (const float*)d_in[0];
    const float* cosb   = (const float*)d_in[1];
    const float* sinb   = (const float*)d_in[2];
    // d_in[3] = attn_mask (all zeros, unused by reference) — ignored
    const float* Wq     = (const float*)d_in[4];
    const float* Wk     = (const float*)d_in[5];
    float* out = (float*)d_out;

    char* ws = (char*)d_ws;
    _Float16* Xh = (_Float16*)ws;                                   // 8 MiB
    _Float16* Wh = (_Float16*)(ws + 8388608);                       // 10 MiB
    _Float16* qf = (_Float16*)(ws + 8388608 + 10485760);            // 8 MiB
    _Float16* kf = (_Float16*)(ws + 8388608 + 10485760 + 8388608);  // 2 MiB

    convert_kernel<<<4608, 256, 0, stream>>>(hidden, Wq, Wk, Xh, Wh);
    gemm1_kernel<<<dim3(16, 20), 256, 0, stream>>>(Xh, Wh, cosb, sinb, qf, kf);
    attn_kernel<<<dim3(128, 32), 512, 0, stream>>>(qf, kf, out);
}

// Round 2
// 677.385 us; speedup vs baseline: 1.0368x; 1.0368x over previous
//
#include <hip/hip_runtime.h>
#include <hip/hip_bf16.h>

typedef _Float16 half8 __attribute__((ext_vector_type(8)));
typedef float floatx4 __attribute__((ext_vector_type(4)));

#define SEQ 2048
#define DIM 2048
#define HQ 32
#define HKV 8
#define HD 64
#define NQ (HQ*HD)    /* 2048 */
#define NK (HKV*HD)   /* 512  */
#define NTOT (NQ+NK)  /* 2560 */
#define LOG2E 1.44269504088896340736f

#define GLOAD_LDS16(g, l) \
    __builtin_amdgcn_global_load_lds( \
        (const __attribute__((address_space(1))) void*)(g), \
        (__attribute__((address_space(3))) void*)(l), 16, 0, 0)

// ---------------------------------------------------------------------------
// Kernel 0: fp32 -> fp16 conversion, vectorized: float4 x2 -> half8 per thread
// ---------------------------------------------------------------------------
__global__ __launch_bounds__(256) void convert_kernel(
    const float* __restrict__ X, const float* __restrict__ Wq,
    const float* __restrict__ Wk, _Float16* __restrict__ Xh,
    _Float16* __restrict__ Wh)
{
    const long c   = (long)blockIdx.x * 256 + threadIdx.x;  // 8-float chunk id
    const long nxc = (long)SEQ * DIM / 8;                   // 524288
    const float* src;
    _Float16* dst;
    if (c < nxc) {
        src = X + c * 8;
        dst = Xh + c * 8;
    } else {
        long f = (c - nxc) * 8;
        src = (f < (long)NQ * DIM) ? Wq + f : Wk + (f - (long)NQ * DIM);
        dst = Wh + f;
    }
    float4 a = ((const float4*)src)[0];
    float4 b = ((const float4*)src)[1];
    half8 h = {(_Float16)a.x, (_Float16)a.y, (_Float16)a.z, (_Float16)a.w,
               (_Float16)b.x, (_Float16)b.y, (_Float16)b.z, (_Float16)b.w};
    *(half8*)dst = h;
}

// ---------------------------------------------------------------------------
// Kernel 1: QK projection GEMM + RoPE. m97-class structure: BM=128, BN=128,
// BK=64. 256 threads = 4 waves (2x2), wave tile 64x64, acc[4][4].
// global_load_lds staging with XOR chunk swizzle applied on the GLOBAL
// address (LDS DMA destination stays linear, per gfx950 constraint).
// Q output is pre-scaled by log2(e) so the attention kernel can use exp2.
// ---------------------------------------------------------------------------
__global__ __launch_bounds__(256) void gemm1_kernel(
    const _Float16* __restrict__ Xh, const _Float16* __restrict__ Wh,
    const float* __restrict__ cosb, const float* __restrict__ sinb,
    _Float16* __restrict__ qout, _Float16* __restrict__ kout)
{
    __shared__ __align__(16) _Float16 lsA[128 * 64];   // 16 KB
    __shared__ __align__(16) _Float16 lsB[128 * 64];   // 16 KB
    const int tid  = threadIdx.x;
    const int lane = tid & 63;
    const int wv   = tid >> 6;
    const int wm   = wv & 1, wn = wv >> 1;       // 2x2 wave grid, 64x64 each
    const int m    = lane & 15, quad = lane >> 4;
    const int s0   = blockIdx.x * 128;
    const int n0   = blockIdx.y * 128;

    floatx4 acc[4][4];
    #pragma unroll
    for (int i = 0; i < 4; i++)
        #pragma unroll
        for (int j = 0; j < 4; j++)
            acc[i][j] = floatx4{0.f, 0.f, 0.f, 0.f};

    for (int k0 = 0; k0 < DIM; k0 += 64) {
        __syncthreads();
        // A: 128 rows x 8 chunks(16B) = 1024 chunks, 4 rounds of 256 threads
        #pragma unroll
        for (int r = 0; r < 4; r++) {
            int c    = r * 256 + tid;
            int row  = c >> 3;
            int chg  = (c & 7) ^ (row & 7);   // swizzled global chunk
            GLOAD_LDS16(Xh + (long)(s0 + row) * DIM + k0 + chg * 8,
                        (char*)lsA + (r * 256 + wv * 64) * 16);
        }
        // B: 128 rows x 8 chunks = 1024 chunks, 4 rounds
        #pragma unroll
        for (int r = 0; r < 4; r++) {
            int c    = r * 256 + tid;
            int row  = c >> 3;
            int chg  = (c & 7) ^ (row & 7);
            GLOAD_LDS16(Wh + (long)(n0 + row) * DIM + k0 + chg * 8,
                        (char*)lsB + (r * 256 + wv * 64) * 16);
        }
        __syncthreads();   // drains vmcnt + lgkmcnt

        #pragma unroll
        for (int kk = 0; kk < 2; kk++) {
            half8 aF[4], bF[4];
            const int pc = ((kk << 2) | quad) ^ (m & 7);
            #pragma unroll
            for (int i = 0; i < 4; i++)
                aF[i] = *(const half8*)(lsA + (wm * 64 + i * 16 + m) * 64 + pc * 8);
            #pragma unroll
            for (int j = 0; j < 4; j++)
                bF[j] = *(const half8*)(lsB + (wn * 64 + j * 16 + m) * 64 + pc * 8);
            #pragma unroll
            for (int i = 0; i < 4; i++)
                #pragma unroll
                for (int j = 0; j < 4; j++)
                    acc[i][j] = __builtin_amdgcn_mfma_f32_16x16x32_f16(
                        aF[i], bF[j], acc[i][j], 0, 0, 0);
        }
    }

    // Epilogue: RoPE + fp16 store. Wave covers 64 cols = one head exactly
    // (n0 multiple of 128, +wn*64). Q additionally scaled by log2(e).
    #pragma unroll
    for (int i = 0; i < 4; i++) {
        #pragma unroll
        for (int reg = 0; reg < 4; reg++) {
            int s = s0 + wm * 64 + i * 16 + quad * 4 + reg;
            #pragma unroll
            for (int j = 0; j < 4; j++) {
                int col = n0 + wn * 64 + j * 16 + m;
                int d   = j * 16 + m;
                float v = acc[i][j][reg];
                float partner = (j < 2) ? -acc[i][j + 2][reg] : acc[i][j - 2][reg];
                float cs = cosb[s * HD + d];
                float sn = sinb[s * HD + d];
                float o  = v * cs + partner * sn;
                if (col < NQ) {
                    int hq = col >> 6;
                    qout[((long)hq * SEQ + s) * HD + d] = (_Float16)(o * LOG2E);
                } else {
                    int hk = (col - NQ) >> 6;
                    kout[((long)hk * SEQ + s) * HD + d] = (_Float16)o;
                }
            }
        }
    }
}

// ---------------------------------------------------------------------------
// Kernel 2: scores + softmax. Block = (32 q-rows, head), 512 threads (8 waves).
// Operand-swapped MFMA: A = K-tile (M = key), B = Q-tile (N = query).
// Each lane holds 4 consecutive keys of ONE query row => scalar softmax state.
// K is loaded ONCE per block and reused for both 16-row q-groups (halves K
// L2 traffic vs 16-row blocks). Output goes through a per-wave XOR-swizzled
// LDS transpose so each wave store instruction writes 1 KB fully contiguous,
// then nontemporal stores bypass L2 entirely (keeps kf L2-resident).
// ---------------------------------------------------------------------------
__global__ __launch_bounds__(512, 2) void attn_kernel(
    const _Float16* __restrict__ qf, const _Float16* __restrict__ kf,
    float* __restrict__ out)
{
    // 128 KB transpose buffer; reduction scratch is unioned into its head
    // (reductions strictly precede transpose use, separated by a barrier).
    __shared__ float lsT[8][16][256];
    float* redm = &lsT[0][0][0];        // [2][8][16] = 256 floats
    float* redl = redm + 256;           // [2][8][16] = 256 floats

    const int tid  = threadIdx.x;
    const int lane = tid & 63;
    const int w    = tid >> 6;      // wave 0..7, owns keys [w*256, w*256+256)
    const int m    = lane & 15, quad = lane >> 4;
    const int qb   = blockIdx.x;    // 0..63
    const int h    = blockIdx.y;    // 0..31
    const int kvh  = h >> 2;
    const int s0   = qb * 32;

    const _Float16* qbase = qf + ((long)h * SEQ + s0) * HD;
    const _Float16* kbase = kf + (long)kvh * SEQ * HD;

    // B operand = Q, two 16-row groups: B[n=lane&15][k=quad*8+j]
    half8 bQ[2][2];
    #pragma unroll
    for (int g = 0; g < 2; g++) {
        bQ[g][0] = *(const half8*)(qbase + (long)(g * 16 + m) * HD + quad * 8);
        bQ[g][1] = *(const half8*)(qbase + (long)(g * 16 + m) * HD + 32 + quad * 8);
    }

    floatx4 acc[2][16];
    // prologue: load ct=0 K tile; 1-deep pipeline over ct
    const _Float16* kp = kbase + (long)(w * 256 + m) * HD + quad * 8;
    half8 aK0 = *(const half8*)(kp);
    half8 aK1 = *(const half8*)(kp + 32);
    #pragma unroll
    for (int ct = 0; ct < 16; ct++) {
        half8 nK0, nK1;
        if (ct < 15) {   // compile-time folded after unroll
            const _Float16* np = kbase + (long)(w * 256 + (ct + 1) * 16 + m) * HD + quad * 8;
            nK0 = *(const half8*)(np);
            nK1 = *(const half8*)(np + 32);
        }
        #pragma unroll
        for (int g = 0; g < 2; g++) {
            floatx4 a = floatx4{0.f, 0.f, 0.f, 0.f};
            a = __builtin_amdgcn_mfma_f32_16x16x32_f16(aK0, bQ[g][0], a, 0, 0, 0);
            a = __builtin_amdgcn_mfma_f32_16x16x32_f16(aK1, bQ[g][1], a, 0, 0, 0);
            acc[g][ct] = a;
        }
        aK0 = nK0;
        aK1 = nK1;
    }

    // ---- softmax (both groups share barriers) ----
    float gmax[2];
    #pragma unroll
    for (int g = 0; g < 2; g++) {
        float lm = acc[g][0][0];
        #pragma unroll
        for (int ct = 0; ct < 16; ct++)
            #pragma unroll
            for (int r = 0; r < 4; r++) lm = fmaxf(lm, acc[g][ct][r]);
        lm = fmaxf(lm, __shfl_xor(lm, 16));
        lm = fmaxf(lm, __shfl_xor(lm, 32));
        if (quad == 0) redm[(g * 8 + w) * 16 + m] = lm;
    }
    __syncthreads();
    #pragma unroll
    for (int g = 0; g < 2; g++) {
        float gm = redm[(g * 8 + 0) * 16 + m];
        #pragma unroll
        for (int ww = 1; ww < 8; ww++)
            gm = fmaxf(gm, redm[(g * 8 + ww) * 16 + m]);
        gmax[g] = gm;
    }

    float inv_[2];
    #pragma unroll
    for (int g = 0; g < 2; g++) {
        float ls = 0.f;
        #pragma unroll
        for (int ct = 0; ct < 16; ct++) {
            #pragma unroll
            for (int r = 0; r < 4; r++) {
                float e = exp2f(acc[g][ct][r] - gmax[g]);  // pre-scaled by log2e
                acc[g][ct][r] = e;
                ls += e;
            }
        }
        ls += __shfl_xor(ls, 16);
        ls += __shfl_xor(ls, 32);
        if (quad == 0) redl[(g * 8 + w) * 16 + m] = ls;
    }
    __syncthreads();
    #pragma unroll
    for (int g = 0; g < 2; g++) {
        float tot = 0.f;
        #pragma unroll
        for (int ww = 0; ww < 8; ww++) tot += redl[(g * 8 + ww) * 16 + m];
        inv_[g] = 1.0f / tot;
    }
    __syncthreads();   // everyone done reading redm/redl before lsT overwrite

    // ---- store via per-wave LDS transpose: 1 KB contiguous NT stores ----
    #pragma unroll
    for (int g = 0; g < 2; g++) {
        // scatter own float4s into swizzled slots (2-way bank alias = free)
        #pragma unroll
        for (int ct = 0; ct < 16; ct++) {
            floatx4 v = acc[g][ct];
            v[0] *= inv_[g]; v[1] *= inv_[g]; v[2] *= inv_[g]; v[3] *= inv_[g];
            int slot = (ct * 4 + quad) ^ m;   // chunk (ct*4+quad) of row m
            *(floatx4*)&lsT[w][m][slot * 4] = v;
        }
        // gather rows: 64 lanes read one full row (swizzle-inverted), store
        // 1 KB contiguous per instruction, nontemporal (bypass L2).
        #pragma unroll
        for (int r = 0; r < 16; r++) {
            int slot = lane ^ r;              // retrieves chunk index == lane
            floatx4 v = *(const floatx4*)&lsT[w][r][slot * 4];
            float* dst = out + ((long)h * SEQ + s0 + g * 16 + r) * SEQ
                             + w * 256 + lane * 4;
            __builtin_nontemporal_store(v, (floatx4*)dst);
        }
        // compiler preserves LDS RAW/WAR order between groups (same array)
    }
}

// ---------------------------------------------------------------------------
extern "C" void kernel_launch(void* const* d_in, const int* in_sizes, int n_in,
                              void* d_out, int out_size, void* d_ws, size_t ws_size,
                              hipStream_t stream) {
    const float* hidden = (const float*)d_in[0];
    const float* cosb   = (const float*)d_in[1];
    const float* sinb   = (const float*)d_in[2];
    // d_in[3] = attn_mask (all zeros, unused by reference) — ignored
    const float* Wq     = (const float*)d_in[4];
    const float* Wk     = (const float*)d_in[5];
    float* out = (float*)d_out;

    char* ws = (char*)d_ws;
    _Float16* Xh = (_Float16*)ws;                                   // 8 MiB
    _Float16* Wh = (_Float16*)(ws + 8388608);                       // 10 MiB
    _Float16* qf = (_Float16*)(ws + 8388608 + 10485760);            // 8 MiB
    _Float16* kf = (_Float16*)(ws + 8388608 + 10485760 + 8388608);  // 2 MiB

    convert_kernel<<<4608, 256, 0, stream>>>(hidden, Wq, Wk, Xh, Wh);
    gemm1_kernel<<<dim3(16, 20), 256, 0, stream>>>(Xh, Wh, cosb, sinb, qf, kf);
    attn_kernel<<<dim3(64, 32), 512, 0, stream>>>(qf, kf, out);
}